// Round 5
// baseline (1326.537 us; speedup 1.0000x reference)
//
#include <hip/hip_runtime.h>
#include <cmath>

#define NN 100000
#define EE 600000
#define DD 128
#define HH 4
#define AA 32
#define CC 32
#define LL 2
#define NB ((NN + 255) / 256)   // scan blocks = 391
#define GEMM_GRID ((NN + 127) / 128)  // 782 blocks, 128 rows each

typedef unsigned short u16;
typedef unsigned int u32;
typedef __attribute__((ext_vector_type(8))) short bf16x8;  // 8 bf16 in 4 VGPRs
typedef __attribute__((ext_vector_type(4))) float f32x4;

#define MFMA(a, b, c) __builtin_amdgcn_mfma_f32_16x16x32_bf16(a, b, c, 0, 0, 0)

// ============================ CSR build ============================
__global__ __launch_bounds__(256) void k_count(const int* __restrict__ ei,
                                               int* __restrict__ cnt) {
  int e = blockIdx.x * 256 + threadIdx.x;
  if (e < EE) atomicAdd(&cnt[ei[EE + e]], 1);
}

__global__ __launch_bounds__(256) void k_scan1(const int* __restrict__ cnt,
                                               int* __restrict__ row_ptr,
                                               int* __restrict__ bsum) {
  __shared__ int buf[256];
  int b = blockIdx.x, t = threadIdx.x;
  int i = b * 256 + t;
  int v = (i < NN) ? cnt[i] : 0;
  buf[t] = v;
  __syncthreads();
  for (int off = 1; off < 256; off <<= 1) {
    int u = (t >= off) ? buf[t - off] : 0;
    __syncthreads();
    buf[t] += u;
    __syncthreads();
  }
  if (i < NN) row_ptr[i] = buf[t] - v;
  if (t == 255) bsum[b] = buf[255];
}

__global__ __launch_bounds__(512) void k_scan2(const int* __restrict__ bsum,
                                               int* __restrict__ boff) {
  __shared__ int buf[512];
  int t = threadIdx.x;
  int v = (t < NB) ? bsum[t] : 0;
  buf[t] = v;
  __syncthreads();
  for (int off = 1; off < 512; off <<= 1) {
    int u = (t >= off) ? buf[t - off] : 0;
    __syncthreads();
    buf[t] += u;
    __syncthreads();
  }
  if (t < NB) boff[t] = buf[t] - v;
}

__global__ __launch_bounds__(256) void k_scan3(int* __restrict__ row_ptr,
                                               const int* __restrict__ boff,
                                               int* __restrict__ cursor) {
  int b = blockIdx.x, t = threadIdx.x;
  int i = b * 256 + t;
  if (i < NN) {
    int v = row_ptr[i] + boff[b];
    row_ptr[i] = v;
    cursor[i] = v;
  }
  if (i == 0) row_ptr[NN] = EE;
}

// fill CSR src indices AND permute edge_attr rows into CSR order
__global__ __launch_bounds__(256) void k_fill(const int* __restrict__ ei,
                                              int* __restrict__ cursor,
                                              int* __restrict__ csr_src,
                                              float* __restrict__ ea_perm,
                                              const float* __restrict__ eattr) {
  int e = blockIdx.x * 256 + threadIdx.x;
  if (e < EE) {
    int d = ei[EE + e];
    int p = atomicAdd(&cursor[d], 1);
    csr_src[p] = ei[e];
    const float4* srow = (const float4*)(eattr + (size_t)e * AA);
    float4* drow = (float4*)(ea_perm + (size_t)p * AA);
#pragma unroll
    for (int i = 0; i < 8; ++i) drow[i] = srow[i];
  }
}

// ================= W prep: fp32 [k][n] -> bf16 hi/lo transposed [n][k] =================
__global__ __launch_bounds__(256) void k_wprep(const float* __restrict__ Wl,
                                               const float* __restrict__ Wr,
                                               const float* __restrict__ Wlin,
                                               u16* __restrict__ wth,
                                               u16* __restrict__ wtl) {
  int b = blockIdx.x;  // 6*64 blocks
  int m = b >> 6;
  int layer = m / 3, type = m % 3;
  const float* src =
      (type == 0 ? Wl : type == 1 ? Wr : Wlin) + (size_t)layer * DD * DD;
  u16* dh = wth + (size_t)m * DD * DD;
  u16* dl = wtl + (size_t)m * DD * DD;
  int i = (b & 63) * 256 + threadIdx.x;  // 0..16383
  int k = i >> 7, n = i & 127;
  float x = src[i];
  u32 u = __float_as_uint(x);
  u32 hr = (u + 0x7FFFu + ((u >> 16) & 1u)) & 0xFFFF0000u;  // RNE hi
  float hf = __uint_as_float(hr);
  float d = x - hf;
  u32 u2 = __float_as_uint(d);
  u32 lr = (u2 + 0x7FFFu + ((u2 >> 16) & 1u)) & 0xFFFF0000u;  // RNE lo
  dh[n * DD + k] = (u16)(hr >> 16);
  dl[n * DD + k] = (u16)(lr >> 16);
}

// ===================== MFMA GEMM helpers =====================
__device__ inline void cvt8(const float4& p0, const float4& p1, bf16x8& hi,
                            bf16x8& lo) {
  union { bf16x8 v; u32 u[4]; } H, L;
  float f[8] = {p0.x, p0.y, p0.z, p0.w, p1.x, p1.y, p1.z, p1.w};
#pragma unroll
  for (int i = 0; i < 4; ++i) {
    u32 u0 = __float_as_uint(f[2 * i]), u1 = __float_as_uint(f[2 * i + 1]);
    u32 h0 = u0 & 0xFFFF0000u, h1 = u1 & 0xFFFF0000u;
    H.u[i] = (h0 >> 16) | h1;
    float r0 = f[2 * i] - __uint_as_float(h0);
    float r1 = f[2 * i + 1] - __uint_as_float(h1);
    u32 l0 = __float_as_uint(r0) & 0xFFFF0000u;
    u32 l1 = __float_as_uint(r1) & 0xFFFF0000u;
    L.u[i] = (l0 >> 16) | l1;
  }
  hi = H.v;
  lo = L.v;
}

// A-fragments straight from global fp32 (no LDS), clamped rows for the tail.
__device__ inline void load_a(const float* __restrict__ X, long row0, int wid,
                              int q, int ln, bf16x8 ah[2][4], bf16x8 al[2][4]) {
#pragma unroll
  for (int mt = 0; mt < 2; ++mt) {
    long r = row0 + wid * 32 + mt * 16 + ln;
    if (r > NN - 1) r = NN - 1;
    const float* xp = X + r * DD;
#pragma unroll
    for (int ks = 0; ks < 4; ++ks) {
      float4 p0 = *(const float4*)&xp[ks * 32 + q * 8];
      float4 p1 = *(const float4*)&xp[ks * 32 + q * 8 + 4];
      cvt8(p0, p1, ah[mt][ks], al[mt][ks]);
    }
  }
}

// Stage pre-transposed bf16 W (hi & lo) global -> LDS with XOR swizzle
// byte ^= ((row&7)<<4) (kills the 16-way conflict of the 256B row stride).
__device__ inline void stage_w(const u16* __restrict__ gWh,
                               const u16* __restrict__ gWl, u16* sWh, u16* sWl,
                               int t) {
  const uint4* gh = (const uint4*)gWh;
  const uint4* gl = (const uint4*)gWl;
#pragma unroll
  for (int i = 0; i < 8; ++i) {
    int c = t + 256 * i;       // 16B chunk id, 2048 total
    int row = c >> 4;          // 16 chunks per 256B row
    int bo = (c & 15) * 16;
    int dst = row * 256 + (bo ^ ((row & 7) << 4));
    *(uint4*)((char*)sWh + dst) = gh[c];
    *(uint4*)((char*)sWl + dst) = gl[c];
  }
}

__device__ inline void mfma_compute(const u16* sWh, const u16* sWl,
                                    bf16x8 ah[2][4], bf16x8 al[2][4],
                                    f32x4 acc[2][8], int q, int ln) {
#pragma unroll
  for (int ks = 0; ks < 4; ++ks) {
    int base = ks * 64 + q * 16;
#pragma unroll
    for (int nt = 0; nt < 8; ++nt) {
      int nrow = nt * 16 + ln;
      int off = nrow * 256 + (base ^ ((nrow & 7) << 4));
      bf16x8 bh = *(const bf16x8*)((const char*)sWh + off);
      bf16x8 bl = *(const bf16x8*)((const char*)sWl + off);
#pragma unroll
      for (int mt = 0; mt < 2; ++mt) {
        acc[mt][nt] = MFMA(ah[mt][ks], bh, acc[mt][nt]);
        acc[mt][nt] = MFMA(al[mt][ks], bh, acc[mt][nt]);
        acc[mt][nt] = MFMA(ah[mt][ks], bl, acc[mt][nt]);
      }
    }
  }
}

// ===================== fused dual GEMM (xl & xr) =====================
__global__ __launch_bounds__(256, 2) void k_gemm2(
    const float* __restrict__ X, const u16* __restrict__ Wh0,
    const u16* __restrict__ Wl0, const float* __restrict__ b0,
    const u16* __restrict__ Wh1, const u16* __restrict__ Wl1,
    const float* __restrict__ b1, float* __restrict__ O0,
    float* __restrict__ O1) {
  __shared__ u16 sWh[DD * DD];
  __shared__ u16 sWl[DD * DD];
  int t = threadIdx.x, wid = t >> 6, lane = t & 63;
  int q = lane >> 4, ln = lane & 15;
  long row0 = (long)blockIdx.x * 128;

  bf16x8 ah[2][4], al[2][4];
  load_a(X, row0, wid, q, ln, ah, al);

#pragma unroll 1
  for (int rep = 0; rep < 2; ++rep) {
    if (rep) __syncthreads();  // all b-frag reads of prev W done
    stage_w(rep ? Wh1 : Wh0, rep ? Wl1 : Wl0, sWh, sWl, t);
    __syncthreads();

    f32x4 acc[2][8];
    f32x4 zero = {0.f, 0.f, 0.f, 0.f};
#pragma unroll
    for (int mt = 0; mt < 2; ++mt)
#pragma unroll
      for (int nt = 0; nt < 8; ++nt) acc[mt][nt] = zero;

    mfma_compute(sWh, sWl, ah, al, acc, q, ln);

    const float* bias = rep ? b1 : b0;
    float* Out = rep ? O1 : O0;
    float bv[8];
#pragma unroll
    for (int nt = 0; nt < 8; ++nt) bv[nt] = bias[nt * 16 + ln];
#pragma unroll
    for (int mt = 0; mt < 2; ++mt)
#pragma unroll
      for (int nt = 0; nt < 8; ++nt)
#pragma unroll
        for (int rg = 0; rg < 4; ++rg) {
          long r = row0 + wid * 32 + mt * 16 + 4 * q + rg;
          if (r < NN) Out[r * DD + nt * 16 + ln] = acc[mt][nt][rg] + bv[nt];
        }
  }
}

// ============== epilogue GEMM: h=X@W+b, LN, GELU, +resid -> Out ==============
__global__ __launch_bounds__(256, 2) void k_gemm_epi(
    const float* __restrict__ X, const u16* __restrict__ Wh,
    const u16* __restrict__ Wl, const float* __restrict__ bias,
    const float* __restrict__ resid, float* __restrict__ Out,
    const float* __restrict__ gamma, const float* __restrict__ beta) {
  __shared__ u16 sWh[DD * DD];
  __shared__ u16 sWl[DD * DD];
  int t = threadIdx.x, wid = t >> 6, lane = t & 63;
  int q = lane >> 4, ln = lane & 15;
  long row0 = (long)blockIdx.x * 128;

  bf16x8 ah[2][4], al[2][4];
  load_a(X, row0, wid, q, ln, ah, al);
  stage_w(Wh, Wl, sWh, sWl, t);
  __syncthreads();

  f32x4 acc[2][8];
  f32x4 zero = {0.f, 0.f, 0.f, 0.f};
#pragma unroll
  for (int mt = 0; mt < 2; ++mt)
#pragma unroll
    for (int nt = 0; nt < 8; ++nt) acc[mt][nt] = zero;

  mfma_compute(sWh, sWl, ah, al, acc, q, ln);

  float bv[8], gv[8], bev[8];
#pragma unroll
  for (int nt = 0; nt < 8; ++nt) {
    int c = nt * 16 + ln;
    bv[nt] = bias[c];
    gv[nt] = gamma[c];
    bev[nt] = beta[c];
  }

#pragma unroll
  for (int mt = 0; mt < 2; ++mt) {
    float s[4] = {0.f, 0.f, 0.f, 0.f}, ss[4] = {0.f, 0.f, 0.f, 0.f};
#pragma unroll
    for (int nt = 0; nt < 8; ++nt)
#pragma unroll
      for (int rg = 0; rg < 4; ++rg) {
        float v = acc[mt][nt][rg] + bv[nt];
        acc[mt][nt][rg] = v;
        s[rg] += v;
        ss[rg] += v * v;
      }
#pragma unroll
    for (int rg = 0; rg < 4; ++rg) {
#pragma unroll
      for (int m = 1; m < 16; m <<= 1) {
        s[rg] += __shfl_xor(s[rg], m);
        ss[rg] += __shfl_xor(ss[rg], m);
      }
    }
    float mean[4], inv[4];
#pragma unroll
    for (int rg = 0; rg < 4; ++rg) {
      mean[rg] = s[rg] * (1.f / DD);
      float var = ss[rg] * (1.f / DD) - mean[rg] * mean[rg];
      inv[rg] = rsqrtf(var + 1e-5f);
    }
    const float is2 = 0.70710678118654752440f;
#pragma unroll
    for (int nt = 0; nt < 8; ++nt)
#pragma unroll
      for (int rg = 0; rg < 4; ++rg) {
        long r = row0 + wid * 32 + mt * 16 + 4 * q + rg;
        if (r < NN) {
          int c = nt * 16 + ln;
          float u = (acc[mt][nt][rg] - mean[rg]) * inv[rg] * gv[nt] + bev[nt];
          float res = resid[r * DD + c];
          Out[r * DD + c] = res + 0.5f * u * (1.f + erff(u * is2));
        }
      }
  }
}

// ============ fused edge-score + online-softmax aggregation ============
// One wave per destination node. Lane l owns channels 2l,2l+1 (head h=l>>4).
// launch_bounds(256,4): 128-VGPR cap so wreg[32] (64 VGPR) stays resident.
// ea is CSR-permuted (contiguous reads); xl gather is 2-deep prefetched.
__global__ __launch_bounds__(256, 4) void k_attn(
    const int* __restrict__ row_ptr, const int* __restrict__ csr_src,
    const float* __restrict__ ea, const float* __restrict__ We,
    const float* __restrict__ att, const float* __restrict__ xl,
    const float* __restrict__ xr, const float* __restrict__ bias_out,
    float* __restrict__ xo) {
  int t = threadIdx.x;
  int wid = t >> 6, l = t & 63;
  int n = blockIdx.x * 4 + wid;
  int ch = 2 * l;

  float2 wreg[32];  // 64 VGPRs: We columns ch, ch+1
#pragma unroll
  for (int a = 0; a < 32; ++a) wreg[a] = *(const float2*)&We[a * DD + ch];
  float2 av = *(const float2*)&att[ch];
  float2 xrv = *(const float2*)&xr[(size_t)n * DD + ch];

  float m = -INFINITY, d = 0.f;
  float ax = 0.f, ay = 0.f;

  int b = row_ptr[n], e2 = row_ptr[n + 1];
  if (b < e2) {
    int last = e2 - 1;
    // 2-deep pipeline on the xl[src] gather
    int s0 = csr_src[b];
    float2 x0 = *(const float2*)&xl[(size_t)s0 * DD + ch];
    int j1 = (b + 1 <= last) ? b + 1 : last;
    int s1 = csr_src[j1];
    float2 x1 = *(const float2*)&xl[(size_t)s1 * DD + ch];

#pragma unroll 1
    for (int j = b; j < e2; ++j) {
      // issue ea loads first (address depends only on j)
      const float4* ev = (const float4*)(ea + (size_t)j * AA);
      float4 v0 = ev[0], v1 = ev[1], v2 = ev[2], v3 = ev[3];
      float4 v4 = ev[4], v5 = ev[5], v6 = ev[6], v7 = ev[7];

      float2 cxl = x0;
      x0 = x1;
      int j2 = (j + 2 <= last) ? j + 2 : last;
      int s2 = csr_src[j2];
      x1 = *(const float2*)&xl[(size_t)s2 * DD + ch];

      float eax, eay;
      {
        float ex0, ey0;
        ex0 = fmaf(v0.x, wreg[0].x, fmaf(v0.y, wreg[1].x, fmaf(v0.z, wreg[2].x, v0.w * wreg[3].x)));
        ey0 = fmaf(v0.x, wreg[0].y, fmaf(v0.y, wreg[1].y, fmaf(v0.z, wreg[2].y, v0.w * wreg[3].y)));
        ex0 = fmaf(v1.x, wreg[4].x, fmaf(v1.y, wreg[5].x, fmaf(v1.z, wreg[6].x, fmaf(v1.w, wreg[7].x, ex0))));
        ey0 = fmaf(v1.x, wreg[4].y, fmaf(v1.y, wreg[5].y, fmaf(v1.z, wreg[6].y, fmaf(v1.w, wreg[7].y, ey0))));
        ex0 = fmaf(v2.x, wreg[8].x, fmaf(v2.y, wreg[9].x, fmaf(v2.z, wreg[10].x, fmaf(v2.w, wreg[11].x, ex0))));
        ey0 = fmaf(v2.x, wreg[8].y, fmaf(v2.y, wreg[9].y, fmaf(v2.z, wreg[10].y, fmaf(v2.w, wreg[11].y, ey0))));
        ex0 = fmaf(v3.x, wreg[12].x, fmaf(v3.y, wreg[13].x, fmaf(v3.z, wreg[14].x, fmaf(v3.w, wreg[15].x, ex0))));
        ey0 = fmaf(v3.x, wreg[12].y, fmaf(v3.y, wreg[13].y, fmaf(v3.z, wreg[14].y, fmaf(v3.w, wreg[15].y, ey0))));
        ex0 = fmaf(v4.x, wreg[16].x, fmaf(v4.y, wreg[17].x, fmaf(v4.z, wreg[18].x, fmaf(v4.w, wreg[19].x, ex0))));
        ey0 = fmaf(v4.x, wreg[16].y, fmaf(v4.y, wreg[17].y, fmaf(v4.z, wreg[18].y, fmaf(v4.w, wreg[19].y, ey0))));
        ex0 = fmaf(v5.x, wreg[20].x, fmaf(v5.y, wreg[21].x, fmaf(v5.z, wreg[22].x, fmaf(v5.w, wreg[23].x, ex0))));
        ey0 = fmaf(v5.x, wreg[20].y, fmaf(v5.y, wreg[21].y, fmaf(v5.z, wreg[22].y, fmaf(v5.w, wreg[23].y, ey0))));
        ex0 = fmaf(v6.x, wreg[24].x, fmaf(v6.y, wreg[25].x, fmaf(v6.z, wreg[26].x, fmaf(v6.w, wreg[27].x, ex0))));
        ey0 = fmaf(v6.x, wreg[24].y, fmaf(v6.y, wreg[25].y, fmaf(v6.z, wreg[26].y, fmaf(v6.w, wreg[27].y, ey0))));
        ex0 = fmaf(v7.x, wreg[28].x, fmaf(v7.y, wreg[29].x, fmaf(v7.z, wreg[30].x, fmaf(v7.w, wreg[31].x, ex0))));
        ey0 = fmaf(v7.x, wreg[28].y, fmaf(v7.y, wreg[29].y, fmaf(v7.z, wreg[30].y, fmaf(v7.w, wreg[31].y, ey0))));
        eax = ex0;
        eay = ey0;
      }

      float mx = cxl.x + xrv.x + eax;
      float my = cxl.y + xrv.y + eay;
      mx = mx > 0.f ? mx : 0.2f * mx;
      my = my > 0.f ? my : 0.2f * my;
      float lg = av.x * mx + av.y * my;
      lg += __shfl_xor(lg, 1);
      lg += __shfl_xor(lg, 2);
      lg += __shfl_xor(lg, 4);
      lg += __shfl_xor(lg, 8);  // all 16 lanes of head h hold the logit

      float mn = fmaxf(m, lg);
      float sc = __expf(m - mn);  // 0 when m was -inf
      float w = __expf(lg - mn);
      d = d * sc + w;
      ax = fmaf(ax, sc, w * cxl.x);
      ay = fmaf(ay, sc, w * cxl.y);
      m = mn;
    }
  }

  float inv = d > 0.f ? 1.f / d : 0.f;
  float2 bo = *(const float2*)&bias_out[ch];
  float2 o = {fmaf(ax, inv, bo.x), fmaf(ay, inv, bo.y)};
  *(float2*)&xo[(size_t)n * DD + ch] = o;
}

// ============================ launch ============================
extern "C" void kernel_launch(void* const* d_in, const int* in_sizes, int n_in,
                              void* d_out, int out_size, void* d_ws,
                              size_t ws_size, hipStream_t stream) {
  const float* x_in = (const float*)d_in[0];
  const int* ei = (const int*)d_in[1];
  const float* eattr = (const float*)d_in[2];
  const float* W_l = (const float*)d_in[3];
  const float* b_l = (const float*)d_in[4];
  const float* W_r = (const float*)d_in[5];
  const float* b_r = (const float*)d_in[6];
  const float* W_e = (const float*)d_in[7];
  const float* att = (const float*)d_in[8];
  const float* bias_out = (const float*)d_in[9];
  const float* lin_W = (const float*)d_in[10];
  const float* lin_b = (const float*)d_in[11];
  const float* ln_g = (const float*)d_in[12];
  const float* ln_b2 = (const float*)d_in[13];

  float* x = (float*)d_out;  // residual stream lives in d_out

  char* base = (char*)d_ws;
  size_t off = 0;
  auto alloc = [&](size_t bytes) {
    size_t o = off;
    off = (off + bytes + 255) & ~(size_t)255;
    return o;
  };
  float* xl = (float*)(base + alloc((size_t)NN * DD * 4));
  float* xr = (float*)(base + alloc((size_t)NN * DD * 4));
  float* xo = (float*)(base + alloc((size_t)NN * DD * 4));
  float* ea_perm = (float*)(base + alloc((size_t)EE * AA * 4));
  int* cnt = (int*)(base + alloc((size_t)NN * 4));
  int* row_ptr = (int*)(base + alloc((size_t)(NN + 1) * 4));
  int* cursor = (int*)(base + alloc((size_t)NN * 4));
  int* bsum = (int*)(base + alloc((size_t)NB * 4));
  int* boff = (int*)(base + alloc((size_t)NB * 4));
  int* csr_src = (int*)(base + alloc((size_t)EE * 4));
  u16* wth = (u16*)(base + alloc((size_t)6 * DD * DD * 2));
  u16* wtl = (u16*)(base + alloc((size_t)6 * DD * DD * 2));

  // W hi/lo split + transpose (once per call)
  k_wprep<<<6 * 64, 256, 0, stream>>>(W_l, W_r, lin_W, wth, wtl);

  // CSR by destination (layer-invariant; built once per call)
  hipMemsetAsync(cnt, 0, (size_t)NN * 4, stream);
  k_count<<<(EE + 255) / 256, 256, 0, stream>>>(ei, cnt);
  k_scan1<<<NB, 256, 0, stream>>>(cnt, row_ptr, bsum);
  k_scan2<<<1, 512, 0, stream>>>(bsum, boff);
  k_scan3<<<NB, 256, 0, stream>>>(row_ptr, boff, cursor);
  k_fill<<<(EE + 255) / 256, 256, 0, stream>>>(ei, cursor, csr_src, ea_perm,
                                               eattr);

  for (int i = 0; i < LL; ++i) {
    const u16* h_l = wth + (size_t)(i * 3 + 0) * DD * DD;
    const u16* l_l = wtl + (size_t)(i * 3 + 0) * DD * DD;
    const u16* h_r = wth + (size_t)(i * 3 + 1) * DD * DD;
    const u16* l_r = wtl + (size_t)(i * 3 + 1) * DD * DD;
    const u16* h_e = wth + (size_t)(i * 3 + 2) * DD * DD;
    const u16* l_e = wtl + (size_t)(i * 3 + 2) * DD * DD;
    const float* bl_i = b_l + (size_t)i * DD;
    const float* br_i = b_r + (size_t)i * DD;
    const float* We_i = W_e + (size_t)i * AA * DD;
    const float* att_i = att + (size_t)i * HH * CC;
    const float* bo_i = bias_out + (size_t)i * DD;
    const float* lb_i = lin_b + (size_t)i * DD;
    const float* g_i = ln_g + (size_t)i * DD;
    const float* be_i = ln_b2 + (size_t)i * DD;

    const float* xcur = (i == 0) ? x_in : x;  // residual stream input

    k_gemm2<<<GEMM_GRID, 256, 0, stream>>>(xcur, h_l, l_l, bl_i, h_r, l_r,
                                           br_i, xl, xr);
    k_attn<<<NN / 4, 256, 0, stream>>>(row_ptr, csr_src, ea_perm, We_i, att_i,
                                       xl, xr, bo_i, xo);
    k_gemm_epi<<<GEMM_GRID, 256, 0, stream>>>(xo, h_e, l_e, lb_i, xcur, x, g_i,
                                              be_i);
  }
}

// Round 6
// 877.423 us; speedup vs baseline: 1.5119x; 1.5119x over previous
//
#include <hip/hip_runtime.h>
#include <cmath>

#define NN 100000
#define EE 600000
#define DD 128
#define HH 4
#define AA 32
#define CC 32
#define LL 2
#define NB ((NN + 255) / 256)   // scan blocks = 391
#define GEMM_GRID ((NN + 127) / 128)  // 782 blocks, 128 rows each

typedef unsigned short u16;
typedef unsigned int u32;
typedef __attribute__((ext_vector_type(8))) short bf16x8;  // 8 bf16 in 4 VGPRs
typedef __attribute__((ext_vector_type(4))) float f32x4;

#define MFMA(a, b, c) __builtin_amdgcn_mfma_f32_16x16x32_bf16(a, b, c, 0, 0, 0)

// ============================ CSR build ============================
__global__ __launch_bounds__(256) void k_count(const int* __restrict__ ei,
                                               int* __restrict__ cnt) {
  int e = blockIdx.x * 256 + threadIdx.x;
  if (e < EE) atomicAdd(&cnt[ei[EE + e]], 1);
}

__global__ __launch_bounds__(256) void k_scan1(const int* __restrict__ cnt,
                                               int* __restrict__ row_ptr,
                                               int* __restrict__ bsum) {
  __shared__ int buf[256];
  int b = blockIdx.x, t = threadIdx.x;
  int i = b * 256 + t;
  int v = (i < NN) ? cnt[i] : 0;
  buf[t] = v;
  __syncthreads();
  for (int off = 1; off < 256; off <<= 1) {
    int u = (t >= off) ? buf[t - off] : 0;
    __syncthreads();
    buf[t] += u;
    __syncthreads();
  }
  if (i < NN) row_ptr[i] = buf[t] - v;
  if (t == 255) bsum[b] = buf[255];
}

__global__ __launch_bounds__(512) void k_scan2(const int* __restrict__ bsum,
                                               int* __restrict__ boff) {
  __shared__ int buf[512];
  int t = threadIdx.x;
  int v = (t < NB) ? bsum[t] : 0;
  buf[t] = v;
  __syncthreads();
  for (int off = 1; off < 512; off <<= 1) {
    int u = (t >= off) ? buf[t - off] : 0;
    __syncthreads();
    buf[t] += u;
    __syncthreads();
  }
  if (t < NB) boff[t] = buf[t] - v;
}

__global__ __launch_bounds__(256) void k_scan3(int* __restrict__ row_ptr,
                                               const int* __restrict__ boff,
                                               int* __restrict__ cursor) {
  int b = blockIdx.x, t = threadIdx.x;
  int i = b * 256 + t;
  if (i < NN) {
    int v = row_ptr[i] + boff[b];
    row_ptr[i] = v;
    cursor[i] = v;
  }
  if (i == 0) row_ptr[NN] = EE;
}

// fill CSR src indices AND permute edge_attr rows into CSR order
__global__ __launch_bounds__(256) void k_fill(const int* __restrict__ ei,
                                              int* __restrict__ cursor,
                                              int* __restrict__ csr_src,
                                              float* __restrict__ ea_perm,
                                              const float* __restrict__ eattr) {
  int e = blockIdx.x * 256 + threadIdx.x;
  if (e < EE) {
    int d = ei[EE + e];
    int p = atomicAdd(&cursor[d], 1);
    csr_src[p] = ei[e];
    const float4* srow = (const float4*)(eattr + (size_t)e * AA);
    float4* drow = (float4*)(ea_perm + (size_t)p * AA);
#pragma unroll
    for (int i = 0; i < 8; ++i) drow[i] = srow[i];
  }
}

// ================= W prep: fp32 [k][n] -> bf16 hi/lo transposed [n][k] =================
__global__ __launch_bounds__(256) void k_wprep(const float* __restrict__ Wl,
                                               const float* __restrict__ Wr,
                                               const float* __restrict__ Wlin,
                                               u16* __restrict__ wth,
                                               u16* __restrict__ wtl) {
  int b = blockIdx.x;  // 6*64 blocks
  int m = b >> 6;
  int layer = m / 3, type = m % 3;
  const float* src =
      (type == 0 ? Wl : type == 1 ? Wr : Wlin) + (size_t)layer * DD * DD;
  u16* dh = wth + (size_t)m * DD * DD;
  u16* dl = wtl + (size_t)m * DD * DD;
  int i = (b & 63) * 256 + threadIdx.x;  // 0..16383
  int k = i >> 7, n = i & 127;
  float x = src[i];
  u32 u = __float_as_uint(x);
  u32 hr = (u + 0x7FFFu + ((u >> 16) & 1u)) & 0xFFFF0000u;  // RNE hi
  float hf = __uint_as_float(hr);
  float d = x - hf;
  u32 u2 = __float_as_uint(d);
  u32 lr = (u2 + 0x7FFFu + ((u2 >> 16) & 1u)) & 0xFFFF0000u;  // RNE lo
  dh[n * DD + k] = (u16)(hr >> 16);
  dl[n * DD + k] = (u16)(lr >> 16);
}

// ===================== MFMA GEMM helpers =====================
__device__ inline void cvt8(const float4& p0, const float4& p1, bf16x8& hi,
                            bf16x8& lo) {
  union { bf16x8 v; u32 u[4]; } H, L;
  float f[8] = {p0.x, p0.y, p0.z, p0.w, p1.x, p1.y, p1.z, p1.w};
#pragma unroll
  for (int i = 0; i < 4; ++i) {
    u32 u0 = __float_as_uint(f[2 * i]), u1 = __float_as_uint(f[2 * i + 1]);
    u32 h0 = u0 & 0xFFFF0000u, h1 = u1 & 0xFFFF0000u;
    H.u[i] = (h0 >> 16) | h1;
    float r0 = f[2 * i] - __uint_as_float(h0);
    float r1 = f[2 * i + 1] - __uint_as_float(h1);
    u32 l0 = __float_as_uint(r0) & 0xFFFF0000u;
    u32 l1 = __float_as_uint(r1) & 0xFFFF0000u;
    L.u[i] = (l0 >> 16) | l1;
  }
  hi = H.v;
  lo = L.v;
}

// A-fragments straight from global fp32 (no LDS), clamped rows for the tail.
__device__ inline void load_a(const float* __restrict__ X, long row0, int wid,
                              int q, int ln, bf16x8 ah[2][4], bf16x8 al[2][4]) {
#pragma unroll
  for (int mt = 0; mt < 2; ++mt) {
    long r = row0 + wid * 32 + mt * 16 + ln;
    if (r > NN - 1) r = NN - 1;
    const float* xp = X + r * DD;
#pragma unroll
    for (int ks = 0; ks < 4; ++ks) {
      float4 p0 = *(const float4*)&xp[ks * 32 + q * 8];
      float4 p1 = *(const float4*)&xp[ks * 32 + q * 8 + 4];
      cvt8(p0, p1, ah[mt][ks], al[mt][ks]);
    }
  }
}

// Stage pre-transposed bf16 W (hi & lo) global -> LDS with XOR swizzle
// byte ^= ((row&7)<<4) (kills the 16-way conflict of the 256B row stride).
__device__ inline void stage_w(const u16* __restrict__ gWh,
                               const u16* __restrict__ gWl, u16* sWh, u16* sWl,
                               int t) {
  const uint4* gh = (const uint4*)gWh;
  const uint4* gl = (const uint4*)gWl;
#pragma unroll
  for (int i = 0; i < 8; ++i) {
    int c = t + 256 * i;       // 16B chunk id, 2048 total
    int row = c >> 4;          // 16 chunks per 256B row
    int bo = (c & 15) * 16;
    int dst = row * 256 + (bo ^ ((row & 7) << 4));
    *(uint4*)((char*)sWh + dst) = gh[c];
    *(uint4*)((char*)sWl + dst) = gl[c];
  }
}

__device__ inline void mfma_compute(const u16* sWh, const u16* sWl,
                                    bf16x8 ah[2][4], bf16x8 al[2][4],
                                    f32x4 acc[2][8], int q, int ln) {
#pragma unroll
  for (int ks = 0; ks < 4; ++ks) {
    int base = ks * 64 + q * 16;
#pragma unroll
    for (int nt = 0; nt < 8; ++nt) {
      int nrow = nt * 16 + ln;
      int off = nrow * 256 + (base ^ ((nrow & 7) << 4));
      bf16x8 bh = *(const bf16x8*)((const char*)sWh + off);
      bf16x8 bl = *(const bf16x8*)((const char*)sWl + off);
#pragma unroll
      for (int mt = 0; mt < 2; ++mt) {
        acc[mt][nt] = MFMA(ah[mt][ks], bh, acc[mt][nt]);
        acc[mt][nt] = MFMA(al[mt][ks], bh, acc[mt][nt]);
        acc[mt][nt] = MFMA(ah[mt][ks], bl, acc[mt][nt]);
      }
    }
  }
}

// ===================== fused dual GEMM (xl & xr) =====================
__global__ __launch_bounds__(256, 2) void k_gemm2(
    const float* __restrict__ X, const u16* __restrict__ Wh0,
    const u16* __restrict__ Wl0, const float* __restrict__ b0,
    const u16* __restrict__ Wh1, const u16* __restrict__ Wl1,
    const float* __restrict__ b1, float* __restrict__ O0,
    float* __restrict__ O1) {
  __shared__ u16 sWh[DD * DD];
  __shared__ u16 sWl[DD * DD];
  int t = threadIdx.x, wid = t >> 6, lane = t & 63;
  int q = lane >> 4, ln = lane & 15;
  long row0 = (long)blockIdx.x * 128;

  bf16x8 ah[2][4], al[2][4];
  load_a(X, row0, wid, q, ln, ah, al);

#pragma unroll 1
  for (int rep = 0; rep < 2; ++rep) {
    if (rep) __syncthreads();  // all b-frag reads of prev W done
    stage_w(rep ? Wh1 : Wh0, rep ? Wl1 : Wl0, sWh, sWl, t);
    __syncthreads();

    f32x4 acc[2][8];
    f32x4 zero = {0.f, 0.f, 0.f, 0.f};
#pragma unroll
    for (int mt = 0; mt < 2; ++mt)
#pragma unroll
      for (int nt = 0; nt < 8; ++nt) acc[mt][nt] = zero;

    mfma_compute(sWh, sWl, ah, al, acc, q, ln);

    const float* bias = rep ? b1 : b0;
    float* Out = rep ? O1 : O0;
    float bv[8];
#pragma unroll
    for (int nt = 0; nt < 8; ++nt) bv[nt] = bias[nt * 16 + ln];
#pragma unroll
    for (int mt = 0; mt < 2; ++mt)
#pragma unroll
      for (int nt = 0; nt < 8; ++nt)
#pragma unroll
        for (int rg = 0; rg < 4; ++rg) {
          long r = row0 + wid * 32 + mt * 16 + 4 * q + rg;
          if (r < NN) Out[r * DD + nt * 16 + ln] = acc[mt][nt][rg] + bv[nt];
        }
  }
}

// ============== epilogue GEMM: h=X@W+b, LN, GELU, +resid -> Out ==============
__global__ __launch_bounds__(256, 2) void k_gemm_epi(
    const float* __restrict__ X, const u16* __restrict__ Wh,
    const u16* __restrict__ Wl, const float* __restrict__ bias,
    const float* __restrict__ resid, float* __restrict__ Out,
    const float* __restrict__ gamma, const float* __restrict__ beta) {
  __shared__ u16 sWh[DD * DD];
  __shared__ u16 sWl[DD * DD];
  int t = threadIdx.x, wid = t >> 6, lane = t & 63;
  int q = lane >> 4, ln = lane & 15;
  long row0 = (long)blockIdx.x * 128;

  bf16x8 ah[2][4], al[2][4];
  load_a(X, row0, wid, q, ln, ah, al);
  stage_w(Wh, Wl, sWh, sWl, t);
  __syncthreads();

  f32x4 acc[2][8];
  f32x4 zero = {0.f, 0.f, 0.f, 0.f};
#pragma unroll
  for (int mt = 0; mt < 2; ++mt)
#pragma unroll
    for (int nt = 0; nt < 8; ++nt) acc[mt][nt] = zero;

  mfma_compute(sWh, sWl, ah, al, acc, q, ln);

  float bv[8], gv[8], bev[8];
#pragma unroll
  for (int nt = 0; nt < 8; ++nt) {
    int c = nt * 16 + ln;
    bv[nt] = bias[c];
    gv[nt] = gamma[c];
    bev[nt] = beta[c];
  }

#pragma unroll
  for (int mt = 0; mt < 2; ++mt) {
    float s[4] = {0.f, 0.f, 0.f, 0.f}, ss[4] = {0.f, 0.f, 0.f, 0.f};
#pragma unroll
    for (int nt = 0; nt < 8; ++nt)
#pragma unroll
      for (int rg = 0; rg < 4; ++rg) {
        float v = acc[mt][nt][rg] + bv[nt];
        acc[mt][nt][rg] = v;
        s[rg] += v;
        ss[rg] += v * v;
      }
#pragma unroll
    for (int rg = 0; rg < 4; ++rg) {
#pragma unroll
      for (int m = 1; m < 16; m <<= 1) {
        s[rg] += __shfl_xor(s[rg], m);
        ss[rg] += __shfl_xor(ss[rg], m);
      }
    }
    float mean[4], inv[4];
#pragma unroll
    for (int rg = 0; rg < 4; ++rg) {
      mean[rg] = s[rg] * (1.f / DD);
      float var = ss[rg] * (1.f / DD) - mean[rg] * mean[rg];
      inv[rg] = rsqrtf(var + 1e-5f);
    }
    const float is2 = 0.70710678118654752440f;
#pragma unroll
    for (int nt = 0; nt < 8; ++nt)
#pragma unroll
      for (int rg = 0; rg < 4; ++rg) {
        long r = row0 + wid * 32 + mt * 16 + 4 * q + rg;
        if (r < NN) {
          int c = nt * 16 + ln;
          float u = (acc[mt][nt][rg] - mean[rg]) * inv[rg] * gv[nt] + bev[nt];
          float res = resid[r * DD + c];
          Out[r * DD + c] = res + 0.5f * u * (1.f + erff(u * is2));
        }
      }
  }
}

// ============ fused edge-score + online-softmax aggregation ============
// One wave per destination node. Lane l owns channels 2l,2l+1 (head h=l>>4).
// We columns pinned in VGPRs via empty asm (blocks load-sinking). Edges
// processed in PAIRS: two independent logit chains, one shared rescale.
__global__ __launch_bounds__(256, 4) void k_attn(
    const int* __restrict__ row_ptr, const int* __restrict__ csr_src,
    const float* __restrict__ ea, const float* __restrict__ We,
    const float* __restrict__ att, const float* __restrict__ xl,
    const float* __restrict__ xr, const float* __restrict__ bias_out,
    float* __restrict__ xo) {
  int t = threadIdx.x;
  int wid = t >> 6, l = t & 63;
  int n = blockIdx.x * 4 + wid;
  int ch = 2 * l;

  float wx[32], wy[32];  // We columns ch, ch+1 -> 64 VGPRs
#pragma unroll
  for (int a = 0; a < 32; ++a) {
    float2 w = *(const float2*)&We[a * DD + ch];
    wx[a] = w.x;
    wy[a] = w.y;
  }
  // Pin: asm redefines each value, so loads cannot be sunk into the loop
  // and values cannot be rematerialized from memory.
#pragma unroll
  for (int a = 0; a < 32; ++a) {
    asm volatile("" : "+v"(wx[a]), "+v"(wy[a]));
  }
  float2 av = *(const float2*)&att[ch];
  float2 xrv = *(const float2*)&xr[(size_t)n * DD + ch];

  float m = -INFINITY, d = 0.f, ax = 0.f, ay = 0.f;

  int b = __builtin_amdgcn_readfirstlane(row_ptr[n]);
  int e2 = __builtin_amdgcn_readfirstlane(row_ptr[n + 1]);

  int j = b;
#pragma unroll 1
  for (; j + 1 < e2; j += 2) {
    int s0 = __builtin_amdgcn_readfirstlane(csr_src[j]);
    int s1 = __builtin_amdgcn_readfirstlane(csr_src[j + 1]);
    float2 xa = *(const float2*)&xl[(size_t)s0 * DD + ch];
    float2 xb = *(const float2*)&xl[(size_t)s1 * DD + ch];
    const float4* e0 = (const float4*)(ea + (size_t)j * AA);
    const float4* e1 = (const float4*)(ea + (size_t)(j + 1) * AA);

    float p0x = 0.f, p0y = 0.f, p1x = 0.f, p1y = 0.f;
#pragma unroll
    for (int q = 0; q < 8; ++q) {
      float4 u = e0[q];  // wave-uniform broadcast
      float4 v = e1[q];
      p0x = fmaf(u.x, wx[4*q], fmaf(u.y, wx[4*q+1], fmaf(u.z, wx[4*q+2], fmaf(u.w, wx[4*q+3], p0x))));
      p0y = fmaf(u.x, wy[4*q], fmaf(u.y, wy[4*q+1], fmaf(u.z, wy[4*q+2], fmaf(u.w, wy[4*q+3], p0y))));
      p1x = fmaf(v.x, wx[4*q], fmaf(v.y, wx[4*q+1], fmaf(v.z, wx[4*q+2], fmaf(v.w, wx[4*q+3], p1x))));
      p1y = fmaf(v.x, wy[4*q], fmaf(v.y, wy[4*q+1], fmaf(v.z, wy[4*q+2], fmaf(v.w, wy[4*q+3], p1y))));
    }
    float a0x = xa.x + xrv.x + p0x, a0y = xa.y + xrv.y + p0y;
    float a1x = xb.x + xrv.x + p1x, a1y = xb.y + xrv.y + p1y;
    a0x = fmaxf(a0x, 0.2f * a0x);
    a0y = fmaxf(a0y, 0.2f * a0y);
    a1x = fmaxf(a1x, 0.2f * a1x);
    a1y = fmaxf(a1y, 0.2f * a1y);
    float l0 = av.x * a0x + av.y * a0y;
    float l1 = av.x * a1x + av.y * a1y;
    // two independent 16-lane reductions (head h = lanes [16h,16h+16))
    l0 += __shfl_xor(l0, 1);
    l1 += __shfl_xor(l1, 1);
    l0 += __shfl_xor(l0, 2);
    l1 += __shfl_xor(l1, 2);
    l0 += __shfl_xor(l0, 4);
    l1 += __shfl_xor(l1, 4);
    l0 += __shfl_xor(l0, 8);
    l1 += __shfl_xor(l1, 8);

    float mn = fmaxf(m, fmaxf(l0, l1));
    float sc = __expf(m - mn);  // 0 when m was -inf
    float w0 = __expf(l0 - mn);
    float w1 = __expf(l1 - mn);
    d = fmaf(d, sc, w0 + w1);
    ax = fmaf(ax, sc, fmaf(w0, xa.x, w1 * xb.x));
    ay = fmaf(ay, sc, fmaf(w0, xa.y, w1 * xb.y));
    m = mn;
  }
  if (j < e2) {  // odd tail
    int s0 = __builtin_amdgcn_readfirstlane(csr_src[j]);
    float2 xa = *(const float2*)&xl[(size_t)s0 * DD + ch];
    const float4* e0 = (const float4*)(ea + (size_t)j * AA);
    float p0x = 0.f, p0y = 0.f;
#pragma unroll
    for (int q = 0; q < 8; ++q) {
      float4 u = e0[q];
      p0x = fmaf(u.x, wx[4*q], fmaf(u.y, wx[4*q+1], fmaf(u.z, wx[4*q+2], fmaf(u.w, wx[4*q+3], p0x))));
      p0y = fmaf(u.x, wy[4*q], fmaf(u.y, wy[4*q+1], fmaf(u.z, wy[4*q+2], fmaf(u.w, wy[4*q+3], p0y))));
    }
    float a0x = xa.x + xrv.x + p0x, a0y = xa.y + xrv.y + p0y;
    a0x = fmaxf(a0x, 0.2f * a0x);
    a0y = fmaxf(a0y, 0.2f * a0y);
    float l0 = av.x * a0x + av.y * a0y;
    l0 += __shfl_xor(l0, 1);
    l0 += __shfl_xor(l0, 2);
    l0 += __shfl_xor(l0, 4);
    l0 += __shfl_xor(l0, 8);
    float mn = fmaxf(m, l0);
    float sc = __expf(m - mn);
    float w0 = __expf(l0 - mn);
    d = fmaf(d, sc, w0);
    ax = fmaf(ax, sc, w0 * xa.x);
    ay = fmaf(ay, sc, w0 * xa.y);
    m = mn;
  }

  float inv = d > 0.f ? 1.f / d : 0.f;
  float2 bo = *(const float2*)&bias_out[ch];
  float2 o = {fmaf(ax, inv, bo.x), fmaf(ay, inv, bo.y)};
  *(float2*)&xo[(size_t)n * DD + ch] = o;
}

// ============================ launch ============================
extern "C" void kernel_launch(void* const* d_in, const int* in_sizes, int n_in,
                              void* d_out, int out_size, void* d_ws,
                              size_t ws_size, hipStream_t stream) {
  const float* x_in = (const float*)d_in[0];
  const int* ei = (const int*)d_in[1];
  const float* eattr = (const float*)d_in[2];
  const float* W_l = (const float*)d_in[3];
  const float* b_l = (const float*)d_in[4];
  const float* W_r = (const float*)d_in[5];
  const float* b_r = (const float*)d_in[6];
  const float* W_e = (const float*)d_in[7];
  const float* att = (const float*)d_in[8];
  const float* bias_out = (const float*)d_in[9];
  const float* lin_W = (const float*)d_in[10];
  const float* lin_b = (const float*)d_in[11];
  const float* ln_g = (const float*)d_in[12];
  const float* ln_b2 = (const float*)d_in[13];

  float* x = (float*)d_out;  // residual stream lives in d_out

  char* base = (char*)d_ws;
  size_t off = 0;
  auto alloc = [&](size_t bytes) {
    size_t o = off;
    off = (off + bytes + 255) & ~(size_t)255;
    return o;
  };
  float* xl = (float*)(base + alloc((size_t)NN * DD * 4));
  float* xr = (float*)(base + alloc((size_t)NN * DD * 4));
  float* xo = (float*)(base + alloc((size_t)NN * DD * 4));
  float* ea_perm = (float*)(base + alloc((size_t)EE * AA * 4));
  int* cnt = (int*)(base + alloc((size_t)NN * 4));
  int* row_ptr = (int*)(base + alloc((size_t)(NN + 1) * 4));
  int* cursor = (int*)(base + alloc((size_t)NN * 4));
  int* bsum = (int*)(base + alloc((size_t)NB * 4));
  int* boff = (int*)(base + alloc((size_t)NB * 4));
  int* csr_src = (int*)(base + alloc((size_t)EE * 4));
  u16* wth = (u16*)(base + alloc((size_t)6 * DD * DD * 2));
  u16* wtl = (u16*)(base + alloc((size_t)6 * DD * DD * 2));

  // W hi/lo split + transpose (once per call)
  k_wprep<<<6 * 64, 256, 0, stream>>>(W_l, W_r, lin_W, wth, wtl);

  // CSR by destination (layer-invariant; built once per call)
  hipMemsetAsync(cnt, 0, (size_t)NN * 4, stream);
  k_count<<<(EE + 255) / 256, 256, 0, stream>>>(ei, cnt);
  k_scan1<<<NB, 256, 0, stream>>>(cnt, row_ptr, bsum);
  k_scan2<<<1, 512, 0, stream>>>(bsum, boff);
  k_scan3<<<NB, 256, 0, stream>>>(row_ptr, boff, cursor);
  k_fill<<<(EE + 255) / 256, 256, 0, stream>>>(ei, cursor, csr_src, ea_perm,
                                               eattr);

  for (int i = 0; i < LL; ++i) {
    const u16* h_l = wth + (size_t)(i * 3 + 0) * DD * DD;
    const u16* l_l = wtl + (size_t)(i * 3 + 0) * DD * DD;
    const u16* h_r = wth + (size_t)(i * 3 + 1) * DD * DD;
    const u16* l_r = wtl + (size_t)(i * 3 + 1) * DD * DD;
    const u16* h_e = wth + (size_t)(i * 3 + 2) * DD * DD;
    const u16* l_e = wtl + (size_t)(i * 3 + 2) * DD * DD;
    const float* bl_i = b_l + (size_t)i * DD;
    const float* br_i = b_r + (size_t)i * DD;
    const float* We_i = W_e + (size_t)i * AA * DD;
    const float* att_i = att + (size_t)i * HH * CC;
    const float* bo_i = bias_out + (size_t)i * DD;
    const float* lb_i = lin_b + (size_t)i * DD;
    const float* g_i = ln_g + (size_t)i * DD;
    const float* be_i = ln_b2 + (size_t)i * DD;

    const float* xcur = (i == 0) ? x_in : x;  // residual stream input

    k_gemm2<<<GEMM_GRID, 256, 0, stream>>>(xcur, h_l, l_l, bl_i, h_r, l_r,
                                           br_i, xl, xr);
    k_attn<<<NN / 4, 256, 0, stream>>>(row_ptr, csr_src, ea_perm, We_i, att_i,
                                       xl, xr, bo_i, xo);
    k_gemm_epi<<<GEMM_GRID, 256, 0, stream>>>(xo, h_e, l_e, lb_i, xcur, x, g_i,
                                              be_i);
  }
}